// Round 1
// baseline (426.374 us; speedup 1.0000x reference)
//
#include <hip/hip_runtime.h>
#include <hip/hip_bf16.h>

#define B_  4096
#define F_  26
#define E_  64
#define D_  1664
#define N1_ 1024
#define N2_ 512
#define N3_ 256

typedef __attribute__((ext_vector_type(8))) __bf16 bf16x8;
typedef __attribute__((ext_vector_type(4))) float  f32x4;

__device__ __forceinline__ unsigned short f2b(float x) {
    __hip_bfloat16 h = __float2bfloat16(x);
    return __builtin_bit_cast(unsigned short, h);
}
__device__ __forceinline__ float b2f(unsigned short u) {
    return __uint_as_float(((unsigned)u) << 16);
}

// async global->LDS DMA, 16B per lane; LDS dst is wave-uniform base + lane*16
__device__ __forceinline__ void async_load16(const void* g, void* l) {
    __builtin_amdgcn_global_load_lds(
        (const __attribute__((address_space(1))) void*)g,
        (__attribute__((address_space(3))) void*)l,
        16, 0, 0);
}

__device__ __forceinline__ f32x4 mfma16(bf16x8 a, bf16x8 b, f32x4 c) {
    return __builtin_amdgcn_mfma_f32_16x16x32_bf16(a, b, c, 0, 0, 0);
}

// ---------------------------------------------------------------- gather
// x0[b, f*64+e] = emb[ids[b,f], e], stored bf16
__global__ __launch_bounds__(256) void gather_kernel(
        const int* __restrict__ ids, const float* __restrict__ emb,
        unsigned short* __restrict__ x0b)
{
    const int t  = blockIdx.x * 256 + threadIdx.x;
    const int e4 = t * 4;
    if (e4 >= B_ * D_) return;
    const int b = e4 / D_;
    const int d = e4 - b * D_;
    const int f = d >> 6;
    const int e = d & 63;
    const int id = ids[b * F_ + f];
    const float4 v = *(const float4*)(emb + (size_t)id * E_ + e);
    ushort4 o;
    o.x = f2b(v.x); o.y = f2b(v.y); o.z = f2b(v.z); o.w = f2b(v.w);
    *(ushort4*)(x0b + e4) = o;
}

// ------------------------------------------------- weight transpose + cast
// in: [K,N] f32 row-major  ->  out: [N,K] bf16 row-major. K,N multiples of 32.
__global__ __launch_bounds__(256) void transpose_cast_kernel(
        const float* __restrict__ in, unsigned short* __restrict__ out,
        int K, int N)
{
    __shared__ float tile[32][33];
    const int n0 = blockIdx.x * 32, k0 = blockIdx.y * 32;
    const int tc = threadIdx.x & 31, tr = threadIdx.x >> 5;  // tr: 0..7
    #pragma unroll
    for (int p = 0; p < 4; p++)
        tile[tr + p * 8][tc] = in[(size_t)(k0 + tr + p * 8) * N + n0 + tc];
    __syncthreads();
    #pragma unroll
    for (int p = 0; p < 4; p++) {
        const int n = tr + p * 8;
        out[(size_t)(n0 + n) * K + k0 + tc] = f2b(tile[tc][n]);
    }
}

// -------------------------------------------- cross net + head partial dot
// One block (256 thr) per row. x row lives in registers (7 elems/thread).
// After 3 cross iterations, folds partial[b] = x . out_w[:D]  (x never stored)
__global__ __launch_bounds__(256) void cross_head_kernel(
        const unsigned short* __restrict__ x0b,
        const float* __restrict__ cw, const float* __restrict__ cb,
        const float* __restrict__ out_w, float* __restrict__ partial)
{
    __shared__ float red[4];
    const int b = blockIdx.x;
    const int t = threadIdx.x;
    const int lane = t & 63, w = t >> 6;
    const unsigned short* xr = x0b + (size_t)b * D_;

    float x0r[7], xv[7];
    #pragma unroll
    for (int j = 0; j < 7; j++) {
        const int d = t + j * 256;
        const float v = (d < D_) ? b2f(xr[d]) : 0.f;
        x0r[j] = v; xv[j] = v;
    }
    for (int i = 0; i < 3; i++) {
        float s = 0.f;
        #pragma unroll
        for (int j = 0; j < 7; j++) {
            const int d = t + j * 256;
            if (d < D_) s += xv[j] * cw[i * D_ + d];
        }
        #pragma unroll
        for (int off = 32; off > 0; off >>= 1) s += __shfl_down(s, off, 64);
        __syncthreads();
        if (lane == 0) red[w] = s;
        __syncthreads();
        const float st = red[0] + red[1] + red[2] + red[3];
        #pragma unroll
        for (int j = 0; j < 7; j++) {
            const int d = t + j * 256;
            if (d < D_) xv[j] = x0r[j] * st + cb[i * D_ + d] + xv[j];
        }
    }
    float s = 0.f;
    #pragma unroll
    for (int j = 0; j < 7; j++) {
        const int d = t + j * 256;
        if (d < D_) s += xv[j] * out_w[d];
    }
    #pragma unroll
    for (int off = 32; off > 0; off >>= 1) s += __shfl_down(s, off, 64);
    __syncthreads();
    if (lane == 0) red[w] = s;
    __syncthreads();
    if (t == 0) partial[b] = red[0] + red[1] + red[2] + red[3];
}

// ------------------------------------------------------------- MFMA GEMM
// C[M,N] = relu(A[M,K] @ Bt[N,K]^T + bias), all bf16 in / bf16 out, fp32 acc.
// 16x16x32 bf16 MFMA; 4 waves in 2x2; BK=32; global_load_lds width-16 staging.
template<int BM, int BN>
__global__ __launch_bounds__(256) void gemm_bias_relu(
        const unsigned short* __restrict__ A,
        const unsigned short* __restrict__ Bt,
        const float* __restrict__ bias,
        unsigned short* __restrict__ C,
        int M, int N, int K)
{
    constexpr int BK = 32;
    constexpr int WM = BM / 2, WN = BN / 2;
    constexpr int TI = WM / 16, TJ = WN / 16;
    constexpr int CA = BM / 64, CB = BN / 64;   // 1KB chunks per wave

    __shared__ unsigned short sA[BM * BK];
    __shared__ unsigned short sB[BN * BK];

    const int t    = threadIdx.x;
    const int lane = t & 63;
    const int w    = t >> 6;
    const int m0   = blockIdx.y * BM;
    const int n0   = blockIdx.x * BN;
    const int wm   = (w >> 1) * WM;
    const int wn   = (w & 1) * WN;

    // staging lane mapping within a 1KB (16-row x 64B) chunk:
    const int srow = lane >> 2;         // 0..15
    const int scol = (lane & 3) * 8;    // elem col: 0,8,16,24

    f32x4 acc[TI][TJ] = {};

    for (int k0 = 0; k0 < K; k0 += BK) {
        #pragma unroll
        for (int c = 0; c < CA; c++) {
            const int chunk = w * CA + c;
            const unsigned short* g =
                A + (size_t)(m0 + chunk * 16 + srow) * K + k0 + scol;
            async_load16(g, &sA[chunk * 512]);   // lds idx = chunk*512 + lane*8
        }
        #pragma unroll
        for (int c = 0; c < CB; c++) {
            const int chunk = w * CB + c;
            const unsigned short* g =
                Bt + (size_t)(n0 + chunk * 16 + srow) * K + k0 + scol;
            async_load16(g, &sB[chunk * 512]);
        }
        __syncthreads();   // compiler emits s_waitcnt vmcnt(0) before barrier

        bf16x8 af[TI], bf[TJ];
        #pragma unroll
        for (int i = 0; i < TI; i++)
            af[i] = *(const bf16x8*)&sA[(wm + i * 16 + (lane & 15)) * BK + (lane >> 4) * 8];
        #pragma unroll
        for (int j = 0; j < TJ; j++)
            bf[j] = *(const bf16x8*)&sB[(wn + j * 16 + (lane & 15)) * BK + (lane >> 4) * 8];
        #pragma unroll
        for (int i = 0; i < TI; i++)
            #pragma unroll
            for (int j = 0; j < TJ; j++)
                acc[i][j] = mfma16(af[i], bf[j], acc[i][j]);
        __syncthreads();
    }

    // epilogue: C/D layout col=lane&15, row=(lane>>4)*4+reg
    #pragma unroll
    for (int i = 0; i < TI; i++) {
        const int r0 = m0 + wm + i * 16 + (lane >> 4) * 4;
        #pragma unroll
        for (int j = 0; j < TJ; j++) {
            const int col = n0 + wn + j * 16 + (lane & 15);
            const float bv = bias[col];
            #pragma unroll
            for (int r = 0; r < 4; r++) {
                float v = acc[i][j][r] + bv;
                v = fmaxf(v, 0.f);
                C[(size_t)(r0 + r) * N + col] = f2b(v);
            }
        }
    }
}

// ---------------------------------------------------------------- head
// out[b] = sigmoid(partial[b] + h3[b,:] . out_w[D:D+256] + out_b)
__global__ __launch_bounds__(256) void head_kernel(
        const float* __restrict__ partial, const unsigned short* __restrict__ h3,
        const float* __restrict__ out_w, const float* __restrict__ out_b,
        float* __restrict__ out)
{
    const int gw   = (blockIdx.x * 256 + threadIdx.x) >> 6;  // one wave per row
    const int lane = threadIdx.x & 63;
    if (gw >= B_) return;
    float s = 0.f;
    #pragma unroll
    for (int q = 0; q < 4; q++) {
        const int j = lane + q * 64;
        s += b2f(h3[(size_t)gw * N3_ + j]) * out_w[D_ + j];
    }
    #pragma unroll
    for (int off = 32; off > 0; off >>= 1) s += __shfl_down(s, off, 64);
    if (lane == 0) {
        const float logit = partial[gw] + s + out_b[0];
        out[gw] = 1.f / (1.f + expf(-logit));
    }
}

extern "C" void kernel_launch(void* const* d_in, const int* in_sizes, int n_in,
                              void* d_out, int out_size, void* d_ws, size_t ws_size,
                              hipStream_t stream)
{
    (void)in_sizes; (void)n_in; (void)out_size; (void)ws_size;
    const int*   ids     = (const int*)  d_in[0];
    const float* emb     = (const float*)d_in[1];
    const float* cross_w = (const float*)d_in[2];
    const float* cross_b = (const float*)d_in[3];
    const float* w1      = (const float*)d_in[4];
    const float* b1      = (const float*)d_in[5];
    const float* w2      = (const float*)d_in[6];
    const float* b2      = (const float*)d_in[7];
    const float* w3      = (const float*)d_in[8];
    const float* b3      = (const float*)d_in[9];
    const float* out_w   = (const float*)d_in[10];
    const float* out_b   = (const float*)d_in[11];
    float* out = (float*)d_out;

    char* p = (char*)d_ws;
    auto alloc = [&](size_t bytes) {
        char* r = p; p += (bytes + 255) & ~(size_t)255; return r;
    };
    unsigned short* x0b = (unsigned short*)alloc((size_t)B_ * D_ * 2);
    unsigned short* w1t = (unsigned short*)alloc((size_t)D_ * N1_ * 2);
    unsigned short* w2t = (unsigned short*)alloc((size_t)N1_ * N2_ * 2);
    unsigned short* w3t = (unsigned short*)alloc((size_t)N2_ * N3_ * 2);
    unsigned short* h1  = (unsigned short*)alloc((size_t)B_ * N1_ * 2);
    unsigned short* h2  = (unsigned short*)alloc((size_t)B_ * N2_ * 2);
    unsigned short* h3  = (unsigned short*)alloc((size_t)B_ * N3_ * 2);
    float* partial      = (float*)alloc((size_t)B_ * 4);

    gather_kernel<<<(B_ * D_ / 4) / 256, 256, 0, stream>>>(ids, emb, x0b);
    transpose_cast_kernel<<<dim3(N1_ / 32, D_  / 32), 256, 0, stream>>>(w1, w1t, D_,  N1_);
    transpose_cast_kernel<<<dim3(N2_ / 32, N1_ / 32), 256, 0, stream>>>(w2, w2t, N1_, N2_);
    transpose_cast_kernel<<<dim3(N3_ / 32, N2_ / 32), 256, 0, stream>>>(w3, w3t, N2_, N3_);
    cross_head_kernel<<<B_, 256, 0, stream>>>(x0b, cross_w, cross_b, out_w, partial);

    gemm_bias_relu<128, 128><<<dim3(N1_ / 128, B_ / 128), 256, 0, stream>>>(
        x0b, w1t, b1, h1, B_, N1_, D_);
    gemm_bias_relu<128, 64><<<dim3(N2_ / 64, B_ / 128), 256, 0, stream>>>(
        h1, w2t, b2, h2, B_, N2_, N1_);
    gemm_bias_relu<64, 64><<<dim3(N3_ / 64, B_ / 64), 256, 0, stream>>>(
        h2, w3t, b3, h3, B_, N3_, N2_);

    head_kernel<<<B_ / 4, 256, 0, stream>>>(partial, h3, out_w, out_b, out);
}

// Round 2
// 395.351 us; speedup vs baseline: 1.0785x; 1.0785x over previous
//
#include <hip/hip_runtime.h>
#include <hip/hip_bf16.h>

#define B_  4096
#define F_  26
#define E_  64
#define D_  1664
#define N1_ 1024
#define N2_ 512
#define N3_ 256

typedef __attribute__((ext_vector_type(8))) __bf16 bf16x8;
typedef __attribute__((ext_vector_type(4))) float  f32x4;

__device__ __forceinline__ unsigned short f2b(float x) {
    __hip_bfloat16 h = __float2bfloat16(x);
    return __builtin_bit_cast(unsigned short, h);
}
__device__ __forceinline__ float b2f(unsigned short u) {
    return __uint_as_float(((unsigned)u) << 16);
}

// async global->LDS DMA: pass WAVE-UNIFORM lds base; HW places lane i at base + i*16B
__device__ __forceinline__ void async_load16(const void* g, void* l) {
    __builtin_amdgcn_global_load_lds(
        (const __attribute__((address_space(1))) void*)g,
        (__attribute__((address_space(3))) void*)l,
        16, 0, 0);
}

__device__ __forceinline__ f32x4 mfma16(bf16x8 a, bf16x8 b, f32x4 c) {
    return __builtin_amdgcn_mfma_f32_16x16x32_bf16(a, b, c, 0, 0, 0);
}

// ------------------------------------------- fused gather + cross + head-partial
// One block per batch row. Loads emb rows directly (fp32), writes x0 bf16 for the
// GEMM, runs the 3 cross iterations in fp32 registers, folds partial = x.out_w[:D].
__global__ __launch_bounds__(256) void gather_cross_kernel(
        const int* __restrict__ ids, const float* __restrict__ emb,
        const float* __restrict__ cw, const float* __restrict__ cb,
        const float* __restrict__ out_w,
        unsigned short* __restrict__ x0b, float* __restrict__ partial)
{
    __shared__ int   sid[F_];
    __shared__ float red[4];
    const int b = blockIdx.x;
    const int t = threadIdx.x;
    const int lane = t & 63, w = t >> 6;

    if (t < F_) sid[t] = ids[b * F_ + t];
    __syncthreads();

    float x0r[7], xv[7];
    #pragma unroll
    for (int j = 0; j < 7; j++) {
        const int d = t + j * 256;
        float v = 0.f;
        if (d < D_) {
            const int f = d >> 6;
            v = emb[(size_t)sid[f] * E_ + (d & 63)];
            x0b[(size_t)b * D_ + d] = f2b(v);
        }
        x0r[j] = v; xv[j] = v;
    }
    for (int i = 0; i < 3; i++) {
        float s = 0.f;
        #pragma unroll
        for (int j = 0; j < 7; j++) {
            const int d = t + j * 256;
            if (d < D_) s += xv[j] * cw[i * D_ + d];
        }
        #pragma unroll
        for (int off = 32; off > 0; off >>= 1) s += __shfl_down(s, off, 64);
        __syncthreads();
        if (lane == 0) red[w] = s;
        __syncthreads();
        const float st = red[0] + red[1] + red[2] + red[3];
        #pragma unroll
        for (int j = 0; j < 7; j++) {
            const int d = t + j * 256;
            if (d < D_) xv[j] = x0r[j] * st + cb[i * D_ + d] + xv[j];
        }
    }
    float s = 0.f;
    #pragma unroll
    for (int j = 0; j < 7; j++) {
        const int d = t + j * 256;
        if (d < D_) s += xv[j] * out_w[d];
    }
    #pragma unroll
    for (int off = 32; off > 0; off >>= 1) s += __shfl_down(s, off, 64);
    __syncthreads();
    if (lane == 0) red[w] = s;
    __syncthreads();
    if (t == 0) partial[b] = red[0] + red[1] + red[2] + red[3];
}

// ------------------------------------------------- weight transpose + cast
// in: [K,N] f32 row-major -> out: [N,K] bf16 row-major. K,N multiples of 32.
__global__ __launch_bounds__(256) void transpose_cast_kernel(
        const float* __restrict__ in, unsigned short* __restrict__ out,
        int K, int N)
{
    __shared__ float tile[32][33];
    const int n0 = blockIdx.x * 32, k0 = blockIdx.y * 32;
    const int tc = threadIdx.x & 31, tr = threadIdx.x >> 5;
    #pragma unroll
    for (int p = 0; p < 4; p++)
        tile[tr + p * 8][tc] = in[(size_t)(k0 + tr + p * 8) * N + n0 + tc];
    __syncthreads();
    #pragma unroll
    for (int p = 0; p < 4; p++) {
        const int n = tr + p * 8;
        out[(size_t)(n0 + n) * K + k0 + tc] = f2b(tile[tc][n]);
    }
}

// ------------------------------------------------------------- MFMA GEMM
// C[M,N] = relu(A[M,K] @ Bt[N,K]^T + bias). bf16 in/out, fp32 acc.
// 16x16x32 MFMA, 4 waves (2x2), two BK=32 slabs per barrier pair (KU=2).
// Grid must be (N/BN, M/BM) with M/BM divisible by 8 (XCD swizzle).
template<int BM, int BN>
__global__ __launch_bounds__(256) void gemm_bias_relu(
        const unsigned short* __restrict__ A,
        const unsigned short* __restrict__ Bt,
        const float* __restrict__ bias,
        unsigned short* __restrict__ C,
        int M, int N, int K)
{
    constexpr int WM = BM / 2, WN = BN / 2;
    constexpr int TI = WM / 16, TJ = WN / 16;
    constexpr int nA = BM / 16, nB = BN / 16, nAB = nA + nB;
    constexpr int TOTC = 2 * nAB;     // 1KB chunks per 64-k outer iter

    __shared__ unsigned short sA[2 * BM * 32];
    __shared__ unsigned short sB[2 * BN * 32];

    const int t    = threadIdx.x;
    const int lane = t & 63;
    const int w    = t >> 6;

    // XCD-aware swizzle: xcd = i%8 owns a contiguous band of M-tiles
    const int i    = blockIdx.y * gridDim.x + blockIdx.x;
    const int xcd  = i & 7;
    const int s    = i >> 3;
    const int ypg  = gridDim.y >> 3;           // M-tiles per xcd band
    const int ty   = xcd * ypg + s / gridDim.x;
    const int tx   = s - (s / gridDim.x) * gridDim.x;
    const int m0   = ty * BM;
    const int n0   = tx * BN;
    const int wm   = (w >> 1) * WM;
    const int wn   = (w & 1) * WN;

    const int srow = lane >> 2;        // 0..15 row within chunk
    const int scol = (lane & 3) * 8;   // 0,8,16,24 elem col within slab

    f32x4 acc[TI][TJ] = {};

    for (int k0 = 0; k0 < K; k0 += 64) {
        #pragma unroll
        for (int c0 = 0; c0 < TOTC; c0 += 4) {
            const int c = c0 + w;
            const int u = c / nAB;             // slab 0/1
            const int r = c - u * nAB;
            if (r < nA) {
                const unsigned short* g =
                    A + (size_t)(m0 + r * 16 + srow) * K + k0 + u * 32 + scol;
                async_load16(g, &sA[u * BM * 32 + r * 512]);
            } else {
                const int rb = r - nA;
                const unsigned short* g =
                    Bt + (size_t)(n0 + rb * 16 + srow) * K + k0 + u * 32 + scol;
                async_load16(g, &sB[u * BN * 32 + rb * 512]);
            }
        }
        __syncthreads();

        #pragma unroll
        for (int u = 0; u < 2; u++) {
            bf16x8 af[TI], bf[TJ];
            #pragma unroll
            for (int ii = 0; ii < TI; ii++)
                af[ii] = *(const bf16x8*)
                    &sA[u * BM * 32 + (wm + ii * 16 + (lane & 15)) * 32 + (lane >> 4) * 8];
            #pragma unroll
            for (int j = 0; j < TJ; j++)
                bf[j] = *(const bf16x8*)
                    &sB[u * BN * 32 + (wn + j * 16 + (lane & 15)) * 32 + (lane >> 4) * 8];
            #pragma unroll
            for (int ii = 0; ii < TI; ii++)
                #pragma unroll
                for (int j = 0; j < TJ; j++)
                    acc[ii][j] = mfma16(af[ii], bf[j], acc[ii][j]);
        }
        __syncthreads();
    }

    // epilogue: C/D layout col=lane&15, row=(lane>>4)*4+reg
    #pragma unroll
    for (int ii = 0; ii < TI; ii++) {
        const int r0 = m0 + wm + ii * 16 + (lane >> 4) * 4;
        #pragma unroll
        for (int j = 0; j < TJ; j++) {
            const int col = n0 + wn + j * 16 + (lane & 15);
            const float bv = bias[col];
            #pragma unroll
            for (int r = 0; r < 4; r++) {
                float v = acc[ii][j][r] + bv;
                v = fmaxf(v, 0.f);
                C[(size_t)(r0 + r) * N + col] = f2b(v);
            }
        }
    }
}

// ---------------------------------------------------------------- head
__global__ __launch_bounds__(256) void head_kernel(
        const float* __restrict__ partial, const unsigned short* __restrict__ h3,
        const float* __restrict__ out_w, const float* __restrict__ out_b,
        float* __restrict__ out)
{
    const int gw   = (blockIdx.x * 256 + threadIdx.x) >> 6;  // one wave per row
    const int lane = threadIdx.x & 63;
    if (gw >= B_) return;
    float s = 0.f;
    #pragma unroll
    for (int q = 0; q < 4; q++) {
        const int j = lane + q * 64;
        s += b2f(h3[(size_t)gw * N3_ + j]) * out_w[D_ + j];
    }
    #pragma unroll
    for (int off = 32; off > 0; off >>= 1) s += __shfl_down(s, off, 64);
    if (lane == 0) {
        const float logit = partial[gw] + s + out_b[0];
        out[gw] = 1.f / (1.f + expf(-logit));
    }
}

extern "C" void kernel_launch(void* const* d_in, const int* in_sizes, int n_in,
                              void* d_out, int out_size, void* d_ws, size_t ws_size,
                              hipStream_t stream)
{
    (void)in_sizes; (void)n_in; (void)out_size; (void)ws_size;
    const int*   ids     = (const int*)  d_in[0];
    const float* emb     = (const float*)d_in[1];
    const float* cross_w = (const float*)d_in[2];
    const float* cross_b = (const float*)d_in[3];
    const float* w1      = (const float*)d_in[4];
    const float* b1      = (const float*)d_in[5];
    const float* w2      = (const float*)d_in[6];
    const float* b2      = (const float*)d_in[7];
    const float* w3      = (const float*)d_in[8];
    const float* b3      = (const float*)d_in[9];
    const float* out_w   = (const float*)d_in[10];
    const float* out_b   = (const float*)d_in[11];
    float* out = (float*)d_out;

    char* p = (char*)d_ws;
    auto alloc = [&](size_t bytes) {
        char* r = p; p += (bytes + 255) & ~(size_t)255; return r;
    };
    unsigned short* x0b = (unsigned short*)alloc((size_t)B_ * D_ * 2);
    unsigned short* w1t = (unsigned short*)alloc((size_t)D_ * N1_ * 2);
    unsigned short* w2t = (unsigned short*)alloc((size_t)N1_ * N2_ * 2);
    unsigned short* w3t = (unsigned short*)alloc((size_t)N2_ * N3_ * 2);
    unsigned short* h1  = (unsigned short*)alloc((size_t)B_ * N1_ * 2);
    unsigned short* h2  = (unsigned short*)alloc((size_t)B_ * N2_ * 2);
    unsigned short* h3  = (unsigned short*)alloc((size_t)B_ * N3_ * 2);
    float* partial      = (float*)alloc((size_t)B_ * 4);

    gather_cross_kernel<<<B_, 256, 0, stream>>>(
        ids, emb, cross_w, cross_b, out_w, x0b, partial);
    transpose_cast_kernel<<<dim3(N1_ / 32, D_  / 32), 256, 0, stream>>>(w1, w1t, D_,  N1_);
    transpose_cast_kernel<<<dim3(N2_ / 32, N1_ / 32), 256, 0, stream>>>(w2, w2t, N1_, N2_);
    transpose_cast_kernel<<<dim3(N3_ / 32, N2_ / 32), 256, 0, stream>>>(w3, w3t, N2_, N3_);

    // 512 blocks each (2/CU): GEMM1 128x64, GEMM2 64x64, GEMM3 64x32
    gemm_bias_relu<128, 64><<<dim3(N1_ / 64, B_ / 128), 256, 0, stream>>>(
        x0b, w1t, b1, h1, B_, N1_, D_);
    gemm_bias_relu<64, 64><<<dim3(N2_ / 64, B_ / 64), 256, 0, stream>>>(
        h1, w2t, b2, h2, B_, N2_, N1_);
    gemm_bias_relu<64, 32><<<dim3(N3_ / 32, B_ / 64), 256, 0, stream>>>(
        h2, w3t, b3, h3, B_, N3_, N2_);

    head_kernel<<<B_ / 4, 256, 0, stream>>>(partial, h3, out_w, out_b, out);
}

// Round 3
// 385.868 us; speedup vs baseline: 1.1050x; 1.0246x over previous
//
#include <hip/hip_runtime.h>
#include <hip/hip_bf16.h>

#define B_  4096
#define F_  26
#define E_  64
#define D_  1664
#define N1_ 1024
#define N2_ 512
#define N3_ 256

typedef __attribute__((ext_vector_type(8))) __bf16 bf16x8;
typedef __attribute__((ext_vector_type(4))) float  f32x4;

__device__ __forceinline__ unsigned short f2b(float x) {
    __hip_bfloat16 h = __float2bfloat16(x);
    return __builtin_bit_cast(unsigned short, h);
}
__device__ __forceinline__ float b2f(unsigned short u) {
    return __uint_as_float(((unsigned)u) << 16);
}

// async global->LDS DMA: pass WAVE-UNIFORM lds base; HW places lane i at base + i*16B
__device__ __forceinline__ void async_load16(const void* g, void* l) {
    __builtin_amdgcn_global_load_lds(
        (const __attribute__((address_space(1))) void*)g,
        (__attribute__((address_space(3))) void*)l,
        16, 0, 0);
}

__device__ __forceinline__ f32x4 mfma16(bf16x8 a, bf16x8 b, f32x4 c) {
    return __builtin_amdgcn_mfma_f32_16x16x32_bf16(a, b, c, 0, 0, 0);
}

// ------------------------------------------- fused gather + cross + head-partial
// One block per batch row. Loads emb rows directly (fp32), writes x0 bf16 for the
// GEMM, runs the 3 cross iterations in fp32 registers, folds partial = x.out_w[:D].
__global__ __launch_bounds__(256) void gather_cross_kernel(
        const int* __restrict__ ids, const float* __restrict__ emb,
        const float* __restrict__ cw, const float* __restrict__ cb,
        const float* __restrict__ out_w,
        unsigned short* __restrict__ x0b, float* __restrict__ partial)
{
    __shared__ int   sid[F_];
    __shared__ float red[4];
    const int b = blockIdx.x;
    const int t = threadIdx.x;
    const int lane = t & 63, w = t >> 6;

    if (t < F_) sid[t] = ids[b * F_ + t];
    __syncthreads();

    float x0r[7], xv[7];
    #pragma unroll
    for (int j = 0; j < 7; j++) {
        const int d = t + j * 256;
        float v = 0.f;
        if (d < D_) {
            const int f = d >> 6;
            v = emb[(size_t)sid[f] * E_ + (d & 63)];
            x0b[(size_t)b * D_ + d] = f2b(v);
        }
        x0r[j] = v; xv[j] = v;
    }
    for (int i = 0; i < 3; i++) {
        float s = 0.f;
        #pragma unroll
        for (int j = 0; j < 7; j++) {
            const int d = t + j * 256;
            if (d < D_) s += xv[j] * cw[i * D_ + d];
        }
        #pragma unroll
        for (int off = 32; off > 0; off >>= 1) s += __shfl_down(s, off, 64);
        __syncthreads();
        if (lane == 0) red[w] = s;
        __syncthreads();
        const float st = red[0] + red[1] + red[2] + red[3];
        #pragma unroll
        for (int j = 0; j < 7; j++) {
            const int d = t + j * 256;
            if (d < D_) xv[j] = x0r[j] * st + cb[i * D_ + d] + xv[j];
        }
    }
    float s = 0.f;
    #pragma unroll
    for (int j = 0; j < 7; j++) {
        const int d = t + j * 256;
        if (d < D_) s += xv[j] * out_w[d];
    }
    #pragma unroll
    for (int off = 32; off > 0; off >>= 1) s += __shfl_down(s, off, 64);
    __syncthreads();
    if (lane == 0) red[w] = s;
    __syncthreads();
    if (t == 0) partial[b] = red[0] + red[1] + red[2] + red[3];
}

// ------------------------------------------------- weight transpose + cast
// in: [K,N] f32 row-major -> out: [N,K] bf16 row-major. K,N multiples of 32.
__global__ __launch_bounds__(256) void transpose_cast_kernel(
        const float* __restrict__ in, unsigned short* __restrict__ out,
        int K, int N)
{
    __shared__ float tile[32][33];
    const int n0 = blockIdx.x * 32, k0 = blockIdx.y * 32;
    const int tc = threadIdx.x & 31, tr = threadIdx.x >> 5;
    #pragma unroll
    for (int p = 0; p < 4; p++)
        tile[tr + p * 8][tc] = in[(size_t)(k0 + tr + p * 8) * N + n0 + tc];
    __syncthreads();
    #pragma unroll
    for (int p = 0; p < 4; p++) {
        const int n = tr + p * 8;
        out[(size_t)(n0 + n) * K + k0 + tc] = f2b(tile[tc][n]);
    }
}

// ------------------------------------------------------------- MFMA GEMM
// C[M,N] = relu(A[M,K] @ Bt[N,K]^T + bias). bf16 in/out, fp32 acc.
// 16x16x32 MFMA, 4 waves (2x2), two BK=32 slabs per barrier pair (KU=2).
// Grid must be (N/BN, M/BM) with M/BM divisible by 8 (XCD swizzle).
// Tiles sized for 1024 blocks = 4 blocks/CU (16 waves/CU latency hiding).
template<int BM, int BN>
__global__ __launch_bounds__(256, 4) void gemm_bias_relu(
        const unsigned short* __restrict__ A,
        const unsigned short* __restrict__ Bt,
        const float* __restrict__ bias,
        unsigned short* __restrict__ C,
        int M, int N, int K)
{
    constexpr int WM = BM / 2, WN = BN / 2;
    constexpr int TI = WM / 16, TJ = WN / 16;
    constexpr int nA = BM / 16, nB = BN / 16, nAB = nA + nB;
    constexpr int TOTC = 2 * nAB;     // 1KB chunks per 64-k outer iter

    __shared__ unsigned short sA[2 * BM * 32];
    __shared__ unsigned short sB[2 * BN * 32];

    const int t    = threadIdx.x;
    const int lane = t & 63;
    const int w    = t >> 6;

    // XCD-aware swizzle: xcd = i%8 owns a contiguous band of M-tiles
    const int i    = blockIdx.y * gridDim.x + blockIdx.x;
    const int xcd  = i & 7;
    const int s    = i >> 3;
    const int ypg  = gridDim.y >> 3;           // M-tiles per xcd band
    const int ty   = xcd * ypg + s / gridDim.x;
    const int tx   = s - (s / gridDim.x) * gridDim.x;
    const int m0   = ty * BM;
    const int n0   = tx * BN;
    const int wm   = (w >> 1) * WM;
    const int wn   = (w & 1) * WN;

    const int srow = lane >> 2;        // 0..15 row within chunk
    const int scol = (lane & 3) * 8;   // 0,8,16,24 elem col within slab

    f32x4 acc[TI][TJ] = {};

    for (int k0 = 0; k0 < K; k0 += 64) {
        #pragma unroll
        for (int c0 = 0; c0 < TOTC; c0 += 4) {
            const int c = c0 + w;
            const int u = c / nAB;             // slab 0/1
            const int r = c - u * nAB;
            if (r < nA) {
                const unsigned short* g =
                    A + (size_t)(m0 + r * 16 + srow) * K + k0 + u * 32 + scol;
                async_load16(g, &sA[u * BM * 32 + r * 512]);
            } else {
                const int rb = r - nA;
                const unsigned short* g =
                    Bt + (size_t)(n0 + rb * 16 + srow) * K + k0 + u * 32 + scol;
                async_load16(g, &sB[u * BN * 32 + rb * 512]);
            }
        }
        __syncthreads();

        #pragma unroll
        for (int u = 0; u < 2; u++) {
            bf16x8 af[TI], bf[TJ];
            #pragma unroll
            for (int ii = 0; ii < TI; ii++)
                af[ii] = *(const bf16x8*)
                    &sA[u * BM * 32 + (wm + ii * 16 + (lane & 15)) * 32 + (lane >> 4) * 8];
            #pragma unroll
            for (int j = 0; j < TJ; j++)
                bf[j] = *(const bf16x8*)
                    &sB[u * BN * 32 + (wn + j * 16 + (lane & 15)) * 32 + (lane >> 4) * 8];
            #pragma unroll
            for (int ii = 0; ii < TI; ii++)
                #pragma unroll
                for (int j = 0; j < TJ; j++)
                    acc[ii][j] = mfma16(af[ii], bf[j], acc[ii][j]);
        }
        __syncthreads();
    }

    // epilogue: C/D layout col=lane&15, row=(lane>>4)*4+reg
    #pragma unroll
    for (int ii = 0; ii < TI; ii++) {
        const int r0 = m0 + wm + ii * 16 + (lane >> 4) * 4;
        #pragma unroll
        for (int j = 0; j < TJ; j++) {
            const int col = n0 + wn + j * 16 + (lane & 15);
            const float bv = bias[col];
            #pragma unroll
            for (int r = 0; r < 4; r++) {
                float v = acc[ii][j][r] + bv;
                v = fmaxf(v, 0.f);
                C[(size_t)(r0 + r) * N + col] = f2b(v);
            }
        }
    }
}

// ---------------------------------------------------------------- head
__global__ __launch_bounds__(256) void head_kernel(
        const float* __restrict__ partial, const unsigned short* __restrict__ h3,
        const float* __restrict__ out_w, const float* __restrict__ out_b,
        float* __restrict__ out)
{
    const int gw   = (blockIdx.x * 256 + threadIdx.x) >> 6;  // one wave per row
    const int lane = threadIdx.x & 63;
    if (gw >= B_) return;
    float s = 0.f;
    #pragma unroll
    for (int q = 0; q < 4; q++) {
        const int j = lane + q * 64;
        s += b2f(h3[(size_t)gw * N3_ + j]) * out_w[D_ + j];
    }
    #pragma unroll
    for (int off = 32; off > 0; off >>= 1) s += __shfl_down(s, off, 64);
    if (lane == 0) {
        const float logit = partial[gw] + s + out_b[0];
        out[gw] = 1.f / (1.f + expf(-logit));
    }
}

extern "C" void kernel_launch(void* const* d_in, const int* in_sizes, int n_in,
                              void* d_out, int out_size, void* d_ws, size_t ws_size,
                              hipStream_t stream)
{
    (void)in_sizes; (void)n_in; (void)out_size; (void)ws_size;
    const int*   ids     = (const int*)  d_in[0];
    const float* emb     = (const float*)d_in[1];
    const float* cross_w = (const float*)d_in[2];
    const float* cross_b = (const float*)d_in[3];
    const float* w1      = (const float*)d_in[4];
    const float* b1      = (const float*)d_in[5];
    const float* w2      = (const float*)d_in[6];
    const float* b2      = (const float*)d_in[7];
    const float* w3      = (const float*)d_in[8];
    const float* b3      = (const float*)d_in[9];
    const float* out_w   = (const float*)d_in[10];
    const float* out_b   = (const float*)d_in[11];
    float* out = (float*)d_out;

    char* p = (char*)d_ws;
    auto alloc = [&](size_t bytes) {
        char* r = p; p += (bytes + 255) & ~(size_t)255; return r;
    };
    unsigned short* x0b = (unsigned short*)alloc((size_t)B_ * D_ * 2);
    unsigned short* w1t = (unsigned short*)alloc((size_t)D_ * N1_ * 2);
    unsigned short* w2t = (unsigned short*)alloc((size_t)N1_ * N2_ * 2);
    unsigned short* w3t = (unsigned short*)alloc((size_t)N2_ * N3_ * 2);
    unsigned short* h1  = (unsigned short*)alloc((size_t)B_ * N1_ * 2);
    unsigned short* h2  = (unsigned short*)alloc((size_t)B_ * N2_ * 2);
    unsigned short* h3  = (unsigned short*)alloc((size_t)B_ * N3_ * 2);
    float* partial      = (float*)alloc((size_t)B_ * 4);

    gather_cross_kernel<<<B_, 256, 0, stream>>>(
        ids, emb, cross_w, cross_b, out_w, x0b, partial);
    transpose_cast_kernel<<<dim3(N1_ / 32, D_  / 32), 256, 0, stream>>>(w1, w1t, D_,  N1_);
    transpose_cast_kernel<<<dim3(N2_ / 32, N1_ / 32), 256, 0, stream>>>(w2, w2t, N1_, N2_);
    transpose_cast_kernel<<<dim3(N3_ / 32, N2_ / 32), 256, 0, stream>>>(w3, w3t, N2_, N3_);

    // 1024 blocks each (4/CU): GEMM1 64x64, GEMM2 64x32, GEMM3 32x32
    gemm_bias_relu<64, 64><<<dim3(N1_ / 64, B_ / 64), 256, 0, stream>>>(
        x0b, w1t, b1, h1, B_, N1_, D_);
    gemm_bias_relu<64, 32><<<dim3(N2_ / 32, B_ / 64), 256, 0, stream>>>(
        h1, w2t, b2, h2, B_, N2_, N1_);
    gemm_bias_relu<32, 32><<<dim3(N3_ / 32, B_ / 32), 256, 0, stream>>>(
        h2, w3t, b3, h3, B_, N3_, N2_);

    head_kernel<<<B_ / 4, 256, 0, stream>>>(partial, h3, out_w, out_b, out);
}

// Round 4
// 380.419 us; speedup vs baseline: 1.1208x; 1.0143x over previous
//
#include <hip/hip_runtime.h>
#include <hip/hip_bf16.h>

#define B_  4096
#define F_  26
#define E_  64
#define D_  1664
#define N1_ 1024
#define N2_ 512
#define N3_ 256

typedef __attribute__((ext_vector_type(8))) __bf16 bf16x8;
typedef __attribute__((ext_vector_type(4))) float  f32x4;

__device__ __forceinline__ unsigned short f2b(float x) {
    __hip_bfloat16 h = __float2bfloat16(x);
    return __builtin_bit_cast(unsigned short, h);
}
__device__ __forceinline__ float b2f(unsigned short u) {
    return __uint_as_float(((unsigned)u) << 16);
}

// async global->LDS DMA: pass WAVE-UNIFORM lds base; HW places lane i at base + i*16B
__device__ __forceinline__ void async_load16(const void* g, void* l) {
    __builtin_amdgcn_global_load_lds(
        (const __attribute__((address_space(1))) void*)g,
        (__attribute__((address_space(3))) void*)l,
        16, 0, 0);
}

__device__ __forceinline__ f32x4 mfma16(bf16x8 a, bf16x8 b, f32x4 c) {
    return __builtin_amdgcn_mfma_f32_16x16x32_bf16(a, b, c, 0, 0, 0);
}

// ------------------------------------------- fused gather + cross + head-partial
// One block per batch row, 8 elems/thread via float4. Writes x0 bf16 for the GEMM,
// runs 3 cross iterations in fp32 registers, folds partial = x.out_w[:D].
__global__ __launch_bounds__(256) void gather_cross_kernel(
        const int* __restrict__ ids, const float* __restrict__ emb,
        const float* __restrict__ cw, const float* __restrict__ cb,
        const float* __restrict__ out_w,
        unsigned short* __restrict__ x0out, float* __restrict__ partial)
{
    __shared__ int   sid[F_];
    __shared__ float red[4];
    const int b = blockIdx.x;
    const int t = threadIdx.x;
    const int lane = t & 63, w = t >> 6;
    constexpr int C4 = D_ / 4;           // 416 float4 chunks per row

    if (t < F_) sid[t] = ids[b * F_ + t];
    __syncthreads();

    const float4* emb4 = (const float4*)emb;
    const float4* cw4  = (const float4*)cw;
    const float4* cb4  = (const float4*)cb;
    const float4* ow4  = (const float4*)out_w;

    float4 x0v[2], xv[2];
    #pragma unroll
    for (int j = 0; j < 2; j++) {
        const int c = t + j * 256;
        float4 v = make_float4(0.f, 0.f, 0.f, 0.f);
        if (c < C4) {
            const int f = c >> 4;                       // 16 chunks per field
            v = emb4[(size_t)sid[f] * 16 + (c & 15)];
            ushort4 o;
            o.x = f2b(v.x); o.y = f2b(v.y); o.z = f2b(v.z); o.w = f2b(v.w);
            ((ushort4*)x0out)[(size_t)b * C4 + c] = o;
        }
        x0v[j] = v; xv[j] = v;
    }
    for (int i = 0; i < 3; i++) {
        float s = 0.f;
        #pragma unroll
        for (int j = 0; j < 2; j++) {
            const int c = t + j * 256;
            if (c < C4) {
                const float4 wv = cw4[i * C4 + c];
                s += xv[j].x * wv.x + xv[j].y * wv.y + xv[j].z * wv.z + xv[j].w * wv.w;
            }
        }
        #pragma unroll
        for (int off = 32; off > 0; off >>= 1) s += __shfl_down(s, off, 64);
        __syncthreads();
        if (lane == 0) red[w] = s;
        __syncthreads();
        const float st = red[0] + red[1] + red[2] + red[3];
        #pragma unroll
        for (int j = 0; j < 2; j++) {
            const int c = t + j * 256;
            if (c < C4) {
                const float4 bv = cb4[i * C4 + c];
                xv[j].x = x0v[j].x * st + bv.x + xv[j].x;
                xv[j].y = x0v[j].y * st + bv.y + xv[j].y;
                xv[j].z = x0v[j].z * st + bv.z + xv[j].z;
                xv[j].w = x0v[j].w * st + bv.w + xv[j].w;
            }
        }
    }
    float s = 0.f;
    #pragma unroll
    for (int j = 0; j < 2; j++) {
        const int c = t + j * 256;
        if (c < C4) {
            const float4 wv = ow4[c];
            s += xv[j].x * wv.x + xv[j].y * wv.y + xv[j].z * wv.z + xv[j].w * wv.w;
        }
    }
    #pragma unroll
    for (int off = 32; off > 0; off >>= 1) s += __shfl_down(s, off, 64);
    __syncthreads();
    if (lane == 0) red[w] = s;
    __syncthreads();
    if (t == 0) partial[b] = red[0] + red[1] + red[2] + red[3];
}

// --------------------------------------- fused weight transpose + cast (all 3)
// [K,N] f32 row-major -> [N,K] bf16 row-major, 32x32 tiles.
// w1: 52x32=1664 tiles, w2: 32x16=512, w3: 16x8=128 -> 2304 blocks.
__global__ __launch_bounds__(256) void transpose_all_kernel(
        const float* __restrict__ w1, const float* __restrict__ w2,
        const float* __restrict__ w3,
        unsigned short* __restrict__ o1, unsigned short* __restrict__ o2,
        unsigned short* __restrict__ o3)
{
    __shared__ float tile[32][33];
    const int bid = blockIdx.x;
    const float* in; unsigned short* out; int K, N, lg, t0;
    if (bid < 1664)      { in = w1; out = o1; K = D_;  N = N1_; lg = 5; t0 = 0;    }
    else if (bid < 2176) { in = w2; out = o2; K = N1_; N = N2_; lg = 4; t0 = 1664; }
    else                 { in = w3; out = o3; K = N2_; N = N3_; lg = 3; t0 = 2176; }
    const int tl = bid - t0;
    const int n0 = (tl & ((1 << lg) - 1)) * 32;
    const int k0 = (tl >> lg) * 32;
    const int tc = threadIdx.x & 31, tr = threadIdx.x >> 5;
    #pragma unroll
    for (int p = 0; p < 4; p++)
        tile[tr + p * 8][tc] = in[(size_t)(k0 + tr + p * 8) * N + n0 + tc];
    __syncthreads();
    #pragma unroll
    for (int p = 0; p < 4; p++) {
        const int n = tr + p * 8;
        out[(size_t)(n0 + n) * K + k0 + tc] = f2b(tile[tc][n]);
    }
}

// ------------------------------------------------------------- MFMA GEMM
// C[M,N] = relu(A[M,K] @ Bt[N,K]^T + bias). bf16 in/out, fp32 acc.
// 16x16x32 MFMA, 4 waves (2x2), KU=BKC/32 slabs per barrier pair.
// Grid (N/BN, M/BM), M/BM divisible by 8 (XCD swizzle). K divisible by BKC.
template<int BM, int BN, int BKC>
__global__ __launch_bounds__(256, 4) void gemm_bias_relu(
        const unsigned short* __restrict__ A,
        const unsigned short* __restrict__ Bt,
        const float* __restrict__ bias,
        unsigned short* __restrict__ C,
        int M, int N, int K)
{
    constexpr int KU = BKC / 32;
    constexpr int WM = BM / 2, WN = BN / 2;
    constexpr int TI = WM / 16, TJ = WN / 16;
    constexpr int nA = BM / 16, nB = BN / 16, nAB = nA + nB;
    constexpr int TOTC = KU * nAB;          // 1KB chunks per barrier period

    __shared__ unsigned short sA[KU * BM * 32];
    __shared__ unsigned short sB[KU * BN * 32];

    const int t    = threadIdx.x;
    const int lane = t & 63;
    const int w    = t >> 6;

    // XCD-aware swizzle: xcd = i%8 owns a contiguous band of M-tiles
    const int i    = blockIdx.y * gridDim.x + blockIdx.x;
    const int xcd  = i & 7;
    const int s    = i >> 3;
    const int ypg  = gridDim.y >> 3;
    const int ty   = xcd * ypg + s / gridDim.x;
    const int tx   = s - (s / gridDim.x) * gridDim.x;
    const int m0   = ty * BM;
    const int n0   = tx * BN;
    const int wm   = (w >> 1) * WM;
    const int wn   = (w & 1) * WN;

    const int srow = lane >> 2;        // 0..15 row within chunk
    const int scol = (lane & 3) * 8;   // 0,8,16,24 elem col within slab

    f32x4 acc[TI][TJ] = {};

    for (int k0 = 0; k0 < K; k0 += BKC) {
        #pragma unroll
        for (int c0 = 0; c0 < TOTC; c0 += 4) {
            const int c = c0 + w;
            const int u = c / nAB;              // slab (wave-uniform)
            const int r = c - u * nAB;
            if (r < nA) {
                const unsigned short* g =
                    A + (size_t)(m0 + r * 16 + srow) * K + k0 + u * 32 + scol;
                async_load16(g, &sA[u * BM * 32 + r * 512]);
            } else {
                const int rb = r - nA;
                const unsigned short* g =
                    Bt + (size_t)(n0 + rb * 16 + srow) * K + k0 + u * 32 + scol;
                async_load16(g, &sB[u * BN * 32 + rb * 512]);
            }
        }
        __syncthreads();

        #pragma unroll
        for (int u = 0; u < KU; u++) {
            bf16x8 af[TI], bf[TJ];
            #pragma unroll
            for (int ii = 0; ii < TI; ii++)
                af[ii] = *(const bf16x8*)
                    &sA[u * BM * 32 + (wm + ii * 16 + (lane & 15)) * 32 + (lane >> 4) * 8];
            #pragma unroll
            for (int j = 0; j < TJ; j++)
                bf[j] = *(const bf16x8*)
                    &sB[u * BN * 32 + (wn + j * 16 + (lane & 15)) * 32 + (lane >> 4) * 8];
            #pragma unroll
            for (int ii = 0; ii < TI; ii++)
                #pragma unroll
                for (int j = 0; j < TJ; j++)
                    acc[ii][j] = mfma16(af[ii], bf[j], acc[ii][j]);
        }
        __syncthreads();
    }

    // epilogue: C/D layout col=lane&15, row=(lane>>4)*4+reg
    #pragma unroll
    for (int ii = 0; ii < TI; ii++) {
        const int r0 = m0 + wm + ii * 16 + (lane >> 4) * 4;
        #pragma unroll
        for (int j = 0; j < TJ; j++) {
            const int col = n0 + wn + j * 16 + (lane & 15);
            const float bv = bias[col];
            #pragma unroll
            for (int r = 0; r < 4; r++) {
                float v = acc[ii][j][r] + bv;
                v = fmaxf(v, 0.f);
                C[(size_t)(r0 + r) * N + col] = f2b(v);
            }
        }
    }
}

// ---------------------------------------------------------------- head
__global__ __launch_bounds__(256) void head_kernel(
        const float* __restrict__ partial, const unsigned short* __restrict__ h3,
        const float* __restrict__ out_w, const float* __restrict__ out_b,
        float* __restrict__ out)
{
    const int gw   = (blockIdx.x * 256 + threadIdx.x) >> 6;  // one wave per row
    const int lane = threadIdx.x & 63;
    if (gw >= B_) return;
    float s = 0.f;
    #pragma unroll
    for (int q = 0; q < 4; q++) {
        const int j = lane + q * 64;
        s += b2f(h3[(size_t)gw * N3_ + j]) * out_w[D_ + j];
    }
    #pragma unroll
    for (int off = 32; off > 0; off >>= 1) s += __shfl_down(s, off, 64);
    if (lane == 0) {
        const float logit = partial[gw] + s + out_b[0];
        out[gw] = 1.f / (1.f + expf(-logit));
    }
}

extern "C" void kernel_launch(void* const* d_in, const int* in_sizes, int n_in,
                              void* d_out, int out_size, void* d_ws, size_t ws_size,
                              hipStream_t stream)
{
    (void)in_sizes; (void)n_in; (void)out_size; (void)ws_size;
    const int*   ids     = (const int*)  d_in[0];
    const float* emb     = (const float*)d_in[1];
    const float* cross_w = (const float*)d_in[2];
    const float* cross_b = (const float*)d_in[3];
    const float* w1      = (const float*)d_in[4];
    const float* b1      = (const float*)d_in[5];
    const float* w2      = (const float*)d_in[6];
    const float* b2      = (const float*)d_in[7];
    const float* w3      = (const float*)d_in[8];
    const float* b3      = (const float*)d_in[9];
    const float* out_w   = (const float*)d_in[10];
    const float* out_b   = (const float*)d_in[11];
    float* out = (float*)d_out;

    char* p = (char*)d_ws;
    auto alloc = [&](size_t bytes) {
        char* r = p; p += (bytes + 255) & ~(size_t)255; return r;
    };
    unsigned short* x0b = (unsigned short*)alloc((size_t)B_ * D_ * 2);
    unsigned short* w1t = (unsigned short*)alloc((size_t)D_ * N1_ * 2);
    unsigned short* w2t = (unsigned short*)alloc((size_t)N1_ * N2_ * 2);
    unsigned short* w3t = (unsigned short*)alloc((size_t)N2_ * N3_ * 2);
    unsigned short* h1  = (unsigned short*)alloc((size_t)B_ * N1_ * 2);
    unsigned short* h2  = (unsigned short*)alloc((size_t)B_ * N2_ * 2);
    unsigned short* h3  = (unsigned short*)alloc((size_t)B_ * N3_ * 2);
    float* partial      = (float*)alloc((size_t)B_ * 4);

    gather_cross_kernel<<<B_, 256, 0, stream>>>(
        ids, emb, cross_w, cross_b, out_w, x0b, partial);
    transpose_all_kernel<<<2304, 256, 0, stream>>>(w1, w2, w3, w1t, w2t, w3t);

    // 1024 blocks each (4/CU), BKC=128 (KU=4 slabs per barrier period)
    gemm_bias_relu<64, 64, 128><<<dim3(N1_ / 64, B_ / 64), 256, 0, stream>>>(
        x0b, w1t, b1, h1, B_, N1_, D_);
    gemm_bias_relu<64, 32, 128><<<dim3(N2_ / 32, B_ / 64), 256, 0, stream>>>(
        h1, w2t, b2, h2, B_, N2_, N1_);
    gemm_bias_relu<32, 32, 128><<<dim3(N3_ / 32, B_ / 32), 256, 0, stream>>>(
        h2, w3t, b3, h3, B_, N3_, N2_);

    head_kernel<<<B_ / 4, 256, 0, stream>>>(partial, h3, out_w, out_b, out);
}